// Round 1
// baseline (151.273 us; speedup 1.0000x reference)
//
#include <hip/hip_runtime.h>

// MaxAbsPool2D: x (32,224,224,96) f32 NHWC, pool 2x2 -> out (32,112,112,96).
// Select the signed value with max |.| in each 2x2 window per channel,
// first-index-wins on ties (match jnp.argmax).

#define B_  32
#define H_  224
#define W_  224
#define C_  96
#define HO_ 112
#define WO_ 112
#define C4_ (C_ / 4)             // 24 float4 per pixel
#define ROWSTRIDE (W_ * C_)      // 21504 floats

__device__ __forceinline__ float sel4(float v0, float v1, float v2, float v3) {
    float v  = v0;
    float av = fabsf(v0);
    float a1 = fabsf(v1);
    if (a1 > av) { v = v1; av = a1; }
    float a2 = fabsf(v2);
    if (a2 > av) { v = v2; av = a2; }
    float a3 = fabsf(v3);
    if (a3 > av) { v = v3; }
    return v;
}

__global__ void __launch_bounds__(256)
maxabspool_kernel(const float* __restrict__ x, float* __restrict__ out, int total4) {
    int idx    = blockIdx.x * blockDim.x + threadIdx.x;
    int stride = gridDim.x * blockDim.x;
    for (int e = idx; e < total4; e += stride) {
        int c4  = e % C4_;
        int pix = e / C4_;
        int wo  = pix % WO_;
        int t   = pix / WO_;
        int ho  = t % HO_;
        int b   = t / HO_;

        const float* p0 = x + ((size_t)((b * H_ + 2 * ho) * W_ + 2 * wo) * C_ + c4 * 4);

        float4 q00 = *(const float4*)(p0);                  // (dy=0, dx=0)
        float4 q01 = *(const float4*)(p0 + C_);             // (dy=0, dx=1)
        float4 q10 = *(const float4*)(p0 + ROWSTRIDE);      // (dy=1, dx=0)
        float4 q11 = *(const float4*)(p0 + ROWSTRIDE + C_); // (dy=1, dx=1)

        float4 r;
        r.x = sel4(q00.x, q01.x, q10.x, q11.x);
        r.y = sel4(q00.y, q01.y, q10.y, q11.y);
        r.z = sel4(q00.z, q01.z, q10.z, q11.z);
        r.w = sel4(q00.w, q01.w, q10.w, q11.w);

        *(float4*)(out + (size_t)e * 4) = r;
    }
}

extern "C" void kernel_launch(void* const* d_in, const int* in_sizes, int n_in,
                              void* d_out, int out_size, void* d_ws, size_t ws_size,
                              hipStream_t stream) {
    const float* x = (const float*)d_in[0];
    float* out = (float*)d_out;

    const int total4 = out_size / 4;         // 9,633,792
    const int block  = 256;
    int grid = 2048;                          // 256 CU * 8 blocks/CU, grid-stride

    maxabspool_kernel<<<grid, block, 0, stream>>>(x, out, total4);
}

// Round 3
// 130.158 us; speedup vs baseline: 1.1622x; 1.1622x over previous
//
#include <hip/hip_runtime.h>

// MaxAbsPool2D: x (32,224,224,96) f32 NHWC, pool 2x2 -> out (32,112,112,96).
// Select the signed value with max |.| in each 2x2 window per channel,
// first-index-wins on ties (match jnp.argmax).
//
// R2: fix nontemporal builtin usage — use clang ext_vector_type(4) float
//     (HIP float4 is a struct; the builtin needs a real vector type).
//     Exact grid (37632x256), one float4/thread, nt loads/stores.

#define B_  32
#define H_  224
#define W_  224
#define C_  96
#define HO_ 112
#define WO_ 112
#define C4_ (C_ / 4)             // 24 float4 per pixel
#define ROWSTRIDE (W_ * C_)      // 21504 floats

typedef float f32x4 __attribute__((ext_vector_type(4)));

__device__ __forceinline__ float sel4(float v0, float v1, float v2, float v3) {
    float v  = v0;
    float av = fabsf(v0);
    float a1 = fabsf(v1);
    if (a1 > av) { v = v1; av = a1; }
    float a2 = fabsf(v2);
    if (a2 > av) { v = v2; av = a2; }
    float a3 = fabsf(v3);
    if (a3 > av) { v = v3; }
    return v;
}

__device__ __forceinline__ f32x4 ntload4(const float* p) {
    return __builtin_nontemporal_load((const f32x4*)p);
}

__global__ void __launch_bounds__(256)
maxabspool_kernel(const float* __restrict__ x, float* __restrict__ out) {
    int e = blockIdx.x * 256 + threadIdx.x;   // exact: grid*256 == total4

    int c4  = e % C4_;
    int pix = e / C4_;
    int wo  = pix % WO_;
    int t   = pix / WO_;
    int ho  = t % HO_;
    int b   = t / HO_;

    const float* p0 = x + ((size_t)((b * H_ + 2 * ho) * W_ + 2 * wo) * C_ + c4 * 4);

    f32x4 q00 = ntload4(p0);                  // (dy=0, dx=0)
    f32x4 q01 = ntload4(p0 + C_);             // (dy=0, dx=1)
    f32x4 q10 = ntload4(p0 + ROWSTRIDE);      // (dy=1, dx=0)
    f32x4 q11 = ntload4(p0 + ROWSTRIDE + C_); // (dy=1, dx=1)

    f32x4 r;
    r.x = sel4(q00.x, q01.x, q10.x, q11.x);
    r.y = sel4(q00.y, q01.y, q10.y, q11.y);
    r.z = sel4(q00.z, q01.z, q10.z, q11.z);
    r.w = sel4(q00.w, q01.w, q10.w, q11.w);

    __builtin_nontemporal_store(r, (f32x4*)(out + (size_t)e * 4));
}

extern "C" void kernel_launch(void* const* d_in, const int* in_sizes, int n_in,
                              void* d_out, int out_size, void* d_ws, size_t ws_size,
                              hipStream_t stream) {
    const float* x = (const float*)d_in[0];
    float* out = (float*)d_out;

    const int total4 = out_size / 4;          // 9,633,792
    const int block  = 256;
    const int grid   = total4 / block;        // 37632, exact

    maxabspool_kernel<<<grid, block, 0, stream>>>(x, out);
}